// Round 4
// baseline (211.158 us; speedup 1.0000x reference)
//
#include <hip/hip_runtime.h>
#include <math.h>

#define BB 32
#define SS 128
#define DIN 16
#define HH 128
#define NBSH (BB*SS*HH)   // 524288

__device__ __forceinline__ float4 f4add(float4 a, float4 b){
    return make_float4(a.x+b.x, a.y+b.y, a.z+b.z, a.w+b.w);
}

// ============ K0: composite conv weights ======================================
// W3[(k*16+d)*128+h] = sum_c w12[h,c,k]*w11[c,d]   (conv1x1 then conv3 collapsed)
// W5[(k*16+d)*128+h] = sum_c w22[h,c,k]*w21[c,d]
// W31T[d*128+h] = w31[h,d];  Beff1[k*128+h] = sum_c w12[h,c,k]*b11[c]; Beff2 sim.
__global__ __launch_bounds__(128) void k_prep(
    const float* __restrict__ w11, const float* __restrict__ b11,
    const float* __restrict__ w12,
    const float* __restrict__ w21, const float* __restrict__ b21,
    const float* __restrict__ w22,
    const float* __restrict__ w31,
    float* __restrict__ W3, float* __restrict__ W5, float* __restrict__ W31T,
    float* __restrict__ Beff1, float* __restrict__ Beff2)
{
    int blk = blockIdx.x; int h = threadIdx.x;
    if (blk < 48){
        int k = blk >> 4, d = blk & 15;
        float acc = 0.f;
        for (int c = 0; c < HH; ++c)
            acc = fmaf(w12[((size_t)h*HH + c)*3 + k], w11[c*DIN + d], acc);
        W3[(k*DIN+d)*HH + h] = acc;
    } else if (blk < 128){
        int kk = blk - 48; int k = kk >> 4, d = kk & 15;
        float acc = 0.f;
        for (int c = 0; c < HH; ++c)
            acc = fmaf(w22[((size_t)h*HH + c)*5 + k], w21[c*DIN + d], acc);
        W5[(k*DIN+d)*HH + h] = acc;
    } else {
        #pragma unroll
        for (int d = 0; d < DIN; ++d) W31T[d*HH + h] = w31[h*DIN + d];
        #pragma unroll
        for (int k = 0; k < 3; ++k){
            float a = 0.f;
            for (int c = 0; c < HH; ++c) a = fmaf(w12[((size_t)h*HH+c)*3+k], b11[c], a);
            Beff1[k*HH + h] = a;
        }
        #pragma unroll
        for (int k = 0; k < 5; ++k){
            float a = 0.f;
            for (int c = 0; c < HH; ++c) a = fmaf(w22[((size_t)h*HH+c)*5+k], b21[c], a);
            Beff2[k*HH + h] = a;
        }
    }
}

// ============ K1: fused front end =============================================
// composite convs (x1,x2,t3 in LDS only) -> fuse GEMM+relu -> x, hsT, hr.
// 256 threads = (h in [0,128)) x (g in {0,1}); block covers 8 rows (2 groups of 4).
__global__ __launch_bounds__(256) void k_front_fuse(
    const float* __restrict__ data,
    const float* __restrict__ W3, const float* __restrict__ W5,
    const float* __restrict__ W31T,
    const float* __restrict__ Beff1, const float* __restrict__ Beff2,
    const float* __restrict__ b12, const float* __restrict__ b22,
    const float* __restrict__ b31,
    const float* __restrict__ wf, const float* __restrict__ bf,
    const float* __restrict__ w1, const float* __restrict__ b1,
    float* __restrict__ x, float* __restrict__ hsT, float* __restrict__ hr)
{
    int blk = blockIdx.x; int b = blk >> 4; int s0 = (blk & 15) * 8;
    int t = threadIdx.x; int h = t & 127; int g = t >> 7; int tg = 4*g;
    __shared__ __align__(16) float dinT[DIN*28];   // [d][r], sp = s0-10+r
    __shared__ float4 xc1[2][HH], xc2[2][HH], xc3[2][HH];
    __shared__ float4 xL[2][HH];

    for (int idx = t; idx < 28*DIN; idx += 256){
        int r = idx >> 4, d = idx & 15;
        int sp = s0 - 10 + r;
        dinT[d*28 + r] = (sp >= 0 && sp < SS) ? data[(b*SS+sp)*DIN + d] : 0.f;
    }
    __syncthreads();

    float acc1[4] = {0,0,0,0}, acc2[4] = {0,0,0,0}, acc3[4] = {0,0,0,0};
    for (int d = 0; d < DIN; ++d){
        const float4* qp = reinterpret_cast<const float4*>(dinT + d*28 + tg);
        float4 q0=qp[0], q1=qp[1], q2=qp[2], q3=qp[3], q4=qp[4], q5=qp[5];
        float qf[24] = {q0.x,q0.y,q0.z,q0.w, q1.x,q1.y,q1.z,q1.w,
                        q2.x,q2.y,q2.z,q2.w, q3.x,q3.y,q3.z,q3.w,
                        q4.x,q4.y,q4.z,q4.w, q5.x,q5.y,q5.z,q5.w};
        #pragma unroll
        for (int k = 0; k < 3; ++k){
            float w = W3[(k*DIN+d)*HH + h];
            #pragma unroll
            for (int tp = 0; tp < 4; ++tp)
                acc1[tp] = fmaf(qf[tp + 3*k + 7], w, acc1[tp]);
        }
        #pragma unroll
        for (int k = 0; k < 5; ++k){
            float w = W5[(k*DIN+d)*HH + h];
            #pragma unroll
            for (int tp = 0; tp < 4; ++tp)
                acc2[tp] = fmaf(qf[tp + 5*k], w, acc2[tp]);
        }
        float w31v = W31T[d*HH + h];
        #pragma unroll
        for (int tp = 0; tp < 4; ++tp)
            acc3[tp] = fmaf(qf[tp + 10], w31v, acc3[tp]);
    }
    // biases (per-tap conv1 bias only where the tap is in-bounds)
    float be1[3] = {Beff1[h], Beff1[HH+h], Beff1[2*HH+h]};
    float be2[5] = {Beff2[h], Beff2[HH+h], Beff2[2*HH+h], Beff2[3*HH+h], Beff2[4*HH+h]};
    float bv12 = b12[h], bv22 = b22[h], bv31 = b31[h];
    float o1[4], o2[4], o3[4];
    #pragma unroll
    for (int tp = 0; tp < 4; ++tp){
        int s = s0 + tg + tp;
        float a1 = acc1[tp] + bv12;
        #pragma unroll
        for (int k = 0; k < 3; ++k)
            if ((unsigned)(s + 3*k - 3) < SS) a1 += be1[k];
        float a2 = acc2[tp] + bv22;
        #pragma unroll
        for (int k = 0; k < 5; ++k)
            if ((unsigned)(s + 5*k - 10) < SS) a2 += be2[k];
        o1[tp] = a1; o2[tp] = a2; o3[tp] = acc3[tp] + bv31;
    }
    xc1[g][h] = make_float4(o1[0],o1[1],o1[2],o1[3]);
    xc2[g][h] = make_float4(o2[0],o2[1],o2[2],o2[3]);
    xc3[g][h] = make_float4(o3[0],o3[1],o3[2],o3[3]);
    __syncthreads();

    // fuse GEMM: x = relu(concat(x1,x2,t3) @ wf + bf)
    float bfv = bf[h];
    float fa[4] = {bfv,bfv,bfv,bfv};
    for (int c = 0; c < HH; ++c){
        float4 a = xc1[g][c]; float w = wf[c*HH + h];
        fa[0]=fmaf(a.x,w,fa[0]); fa[1]=fmaf(a.y,w,fa[1]);
        fa[2]=fmaf(a.z,w,fa[2]); fa[3]=fmaf(a.w,w,fa[3]);
    }
    for (int c = 0; c < HH; ++c){
        float4 a = xc2[g][c]; float w = wf[(HH+c)*HH + h];
        fa[0]=fmaf(a.x,w,fa[0]); fa[1]=fmaf(a.y,w,fa[1]);
        fa[2]=fmaf(a.z,w,fa[2]); fa[3]=fmaf(a.w,w,fa[3]);
    }
    for (int c = 0; c < HH; ++c){
        float4 a = xc3[g][c]; float w = wf[(2*HH+c)*HH + h];
        fa[0]=fmaf(a.x,w,fa[0]); fa[1]=fmaf(a.y,w,fa[1]);
        fa[2]=fmaf(a.z,w,fa[2]); fa[3]=fmaf(a.w,w,fa[3]);
    }
    float4 xv = make_float4(fmaxf(fa[0],0.f), fmaxf(fa[1],0.f),
                            fmaxf(fa[2],0.f), fmaxf(fa[3],0.f));
    size_t base = (size_t)(b*SS + s0 + tg)*HH + h;
    x[base] = xv.x; x[base+HH] = xv.y; x[base+2*HH] = xv.z; x[base+3*HH] = xv.w;
    xL[g][h] = xv;
    __syncthreads();

    // hs (transposed) and hr (+b1)
    float as[4]={0,0,0,0}, ar[4]={0,0,0,0};
    for (int c = 0; c < HH; ++c){
        float4 a = xL[g][c];
        float wsv = w1[c*HH+h], wrv = w1[(HH+c)*HH+h];
        as[0]=fmaf(a.x,wsv,as[0]); as[1]=fmaf(a.y,wsv,as[1]);
        as[2]=fmaf(a.z,wsv,as[2]); as[3]=fmaf(a.w,wsv,as[3]);
        ar[0]=fmaf(a.x,wrv,ar[0]); ar[1]=fmaf(a.y,wrv,ar[1]);
        ar[2]=fmaf(a.z,wrv,ar[2]); ar[3]=fmaf(a.w,wrv,ar[3]);
    }
    float b1v = b1[h];
    *reinterpret_cast<float4*>(hsT + ((size_t)b*HH + h)*SS + s0 + tg) =
        make_float4(as[0], as[1], as[2], as[3]);
    hr[base]      = ar[0] + b1v;
    hr[base+HH]   = ar[1] + b1v;
    hr[base+2*HH] = ar[2] + b1v;
    hr[base+3*HH] = ar[3] + b1v;
}

// ============ K2: edge logits + gumbel argmax -> adj (8-i tile) ===============
__global__ __launch_bounds__(256) void k_adj(
    const float* __restrict__ hsT, const float* __restrict__ hr,
    const float* __restrict__ w2, const float* __restrict__ b2,
    const float* __restrict__ gu, float* __restrict__ adj)
{
    int blk = blockIdx.x; int b = blk >> 4; int i0 = (blk & 15) * 8;
    int t = threadIdx.x; int j = t & 127; int g = t >> 7; int ig = i0 + 4*g;
    __shared__ float4 hrT[2][HH];
    __shared__ float w20L[HH], w21L[HH];
    hrT[g][j] = make_float4(hr[(size_t)(b*SS+ig+0)*HH + j],
                            hr[(size_t)(b*SS+ig+1)*HH + j],
                            hr[(size_t)(b*SS+ig+2)*HH + j],
                            hr[(size_t)(b*SS+ig+3)*HH + j]);
    if (g == 0){ w20L[j] = w2[j*2]; w21L[j] = w2[j*2+1]; }
    __syncthreads();
    const float* hsb = hsT + (size_t)b*HH*SS;
    float d0[4] = {0,0,0,0}, d1[4] = {0,0,0,0};
    #pragma unroll 2
    for (int h = 0; h < HH; ++h){
        float hsv = hsb[h*SS + j];
        float4 hv = hrT[g][h];
        float wa = w20L[h], wb = w21L[h];
        float r0 = fmaxf(hsv + hv.x, 0.f);
        float r1 = fmaxf(hsv + hv.y, 0.f);
        float r2 = fmaxf(hsv + hv.z, 0.f);
        float r3 = fmaxf(hsv + hv.w, 0.f);
        d0[0]=fmaf(r0,wa,d0[0]); d1[0]=fmaf(r0,wb,d1[0]);
        d0[1]=fmaf(r1,wa,d0[1]); d1[1]=fmaf(r1,wb,d1[1]);
        d0[2]=fmaf(r2,wa,d0[2]); d1[2]=fmaf(r2,wb,d1[2]);
        d0[3]=fmaf(r3,wa,d0[3]); d1[3]=fmaf(r3,wb,d1[3]);
    }
    float b20 = b2[0], b21 = b2[1];
    #pragma unroll
    for (int ii = 0; ii < 4; ++ii){
        int i = ig + ii;
        size_t e = (size_t)(b*SS+i)*SS + j;
        float2 uv = *reinterpret_cast<const float2*>(gu + e*2);
        float u0 = fminf(fmaxf(uv.x, 1e-6f), 0.999999f);
        float u1 = fminf(fmaxf(uv.y, 1e-6f), 0.999999f);
        float g0 = -logf(-logf(u0));
        float g1 = -logf(-logf(u1));
        float y0 = d0[ii] + b20 + g0;
        float y1 = d1[ii] + b21 + g1;
        adj[e] = (j > i && y0 >= y1) ? 1.f : 0.f;
    }
}

// ============ K3: fused deg + agg + lin + BN partials (8-col tile) ============
__global__ __launch_bounds__(256) void k_gnn(
    const float* __restrict__ adj, const float* __restrict__ in,
    const float* __restrict__ scale_in, const float* __restrict__ shift_in, int aff,
    const float* __restrict__ wl, const float* __restrict__ bl,
    const float* __restrict__ wr,
    float* __restrict__ outb, float2* __restrict__ part2)
{
    int blk = blockIdx.x; int b = blk >> 4; int j0 = (blk & 15) * 8;
    int t = threadIdx.x; int h = t & 127; int g = t >> 7; int jg = j0 + 4*g;
    __shared__ float4 adjL[2][SS];
    __shared__ float4 red[2][64];
    __shared__ float4 aggL[2][HH], xnL[2][HH];

    adjL[g][h] = *reinterpret_cast<const float4*>(adj + (size_t)(b*SS+h)*SS + jg);
    float sc = aff ? scale_in[h] : 1.f;
    float sh = aff ? shift_in[h] : 0.f;
    __syncthreads();
    if (h < 64) red[g][h] = f4add(adjL[g][h], adjL[g][h+64]);
    __syncthreads();
    for (int off = 32; off; off >>= 1){
        if (h < off) red[g][h] = f4add(red[g][h], red[g][h+off]);
        __syncthreads();
    }
    float4 ds = red[g][0];
    float4 dv = make_float4(1.f/fmaxf(ds.x,1.f), 1.f/fmaxf(ds.y,1.f),
                            1.f/fmaxf(ds.z,1.f), 1.f/fmaxf(ds.w,1.f));
    float a0=0.f, a1=0.f, a2=0.f, a3=0.f;
    const float* inb = in + (size_t)b*SS*HH + h;
    #pragma unroll 4
    for (int i = 0; i < SS; ++i){
        float xv = fmaf(inb[(size_t)i*HH], sc, sh);
        float4 av = adjL[g][i];
        a0=fmaf(av.x,xv,a0); a1=fmaf(av.y,xv,a1);
        a2=fmaf(av.z,xv,a2); a3=fmaf(av.w,xv,a3);
    }
    aggL[g][h] = make_float4(a0*dv.x, a1*dv.y, a2*dv.z, a3*dv.w);
    size_t base = (size_t)(b*SS+jg)*HH + h;
    xnL[g][h] = make_float4(fmaf(in[base],sc,sh), fmaf(in[base+HH],sc,sh),
                            fmaf(in[base+2*HH],sc,sh), fmaf(in[base+3*HH],sc,sh));
    __syncthreads();
    float bv = bl[h];
    float acc[4] = {bv,bv,bv,bv};
    for (int c = 0; c < HH; ++c){
        float4 gg = aggL[g][c]; float4 xv = xnL[g][c];
        float wlv = wl[c*HH+h], wrv = wr[c*HH+h];
        acc[0]=fmaf(gg.x,wlv,acc[0]); acc[0]=fmaf(xv.x,wrv,acc[0]);
        acc[1]=fmaf(gg.y,wlv,acc[1]); acc[1]=fmaf(xv.y,wrv,acc[1]);
        acc[2]=fmaf(gg.z,wlv,acc[2]); acc[2]=fmaf(xv.z,wrv,acc[2]);
        acc[3]=fmaf(gg.w,wlv,acc[3]); acc[3]=fmaf(xv.w,wrv,acc[3]);
    }
    outb[base]      = acc[0];
    outb[base+HH]   = acc[1];
    outb[base+2*HH] = acc[2];
    outb[base+3*HH] = acc[3];
    float psum = acc[0]+acc[1]+acc[2]+acc[3];
    float psq  = acc[0]*acc[0]+acc[1]*acc[1]+acc[2]*acc[2]+acc[3]*acc[3];
    part2[(size_t)(blk*2+g)*HH + h] = make_float2(psum, psq);
}

// ============ K4: BN finalize + capture normalized last row ===================
__global__ __launch_bounds__(256) void k_bnfin(
    const float2* __restrict__ part2, const float* __restrict__ gamma,
    const float* __restrict__ beta, const float* __restrict__ outb,
    float* __restrict__ scale, float* __restrict__ shift, float* __restrict__ ol)
{
    int h = blockIdx.x; int t = threadIdx.x;
    float s1 = 0.f, s2 = 0.f;
    for (int i = t; i < 1024; i += 256){
        float2 v = part2[(size_t)i*HH + h];
        s1 += v.x; s2 += v.y;
    }
    __shared__ float r1[256], r2[256];
    __shared__ float sc_sh[2];
    r1[t] = s1; r2[t] = s2;
    __syncthreads();
    for (int off = 128; off; off >>= 1){
        if (t < off){ r1[t] += r1[t+off]; r2[t] += r2[t+off]; }
        __syncthreads();
    }
    if (t == 0){
        float m = r1[0] * (1.f/4096.f);
        float v = r2[0] * (1.f/4096.f) - m*m;
        v = fmaxf(v, 0.f);
        float sc = gamma[h] / sqrtf(v + 1e-5f);
        float sh = beta[h] - m*sc;
        scale[h] = sc; shift[h] = sh;
        sc_sh[0] = sc; sc_sh[1] = sh;
    }
    __syncthreads();
    if (t < BB){
        float val = outb[((size_t)t*SS + SS-1)*HH + h];
        ol[t*HH + h] = fmaf(val, sc_sh[0], sc_sh[1]);
    }
}

// ============ K5: head (gate -> we -> wo) =====================================
__global__ __launch_bounds__(128) void k_head(
    const float* __restrict__ ol, const float* __restrict__ wg,
    const float* __restrict__ bg, const float* __restrict__ we,
    const float* __restrict__ be, const float* __restrict__ wo,
    const float* __restrict__ bo, float* __restrict__ out)
{
    int b = blockIdx.x; int t = threadIdx.x;
    __shared__ float xw[HH];
    float a = bg[0];
    #pragma unroll
    for (int l = 0; l < 3; ++l) a = fmaf(ol[(l*BB + b)*HH + t], wg[l], a);
    xw[t] = fmaxf(a, 0.f);
    __syncthreads();
    if (t < 64){
        float acc = be[t];
        for (int h = 0; h < HH; ++h) acc = fmaf(xw[h], we[h*64 + t], acc);
        float h2 = fmaxf(acc, 0.f);
        float r = h2 * wo[t];
        #pragma unroll
        for (int off = 32; off; off >>= 1) r += __shfl_down(r, off, 64);
        if (t == 0) out[b] = r + bo[0];
    }
}

// ==============================================================================
extern "C" void kernel_launch(void* const* d_in, const int* in_sizes, int n_in,
                              void* d_out, int out_size, void* d_ws, size_t ws_size,
                              hipStream_t stream)
{
    const float* data = (const float*)d_in[0];
    const float* gu   = (const float*)d_in[1];
    const float* w11  = (const float*)d_in[2];
    const float* b11  = (const float*)d_in[3];
    const float* w12  = (const float*)d_in[4];
    const float* b12  = (const float*)d_in[5];
    const float* w21  = (const float*)d_in[6];
    const float* b21  = (const float*)d_in[7];
    const float* w22  = (const float*)d_in[8];
    const float* b22  = (const float*)d_in[9];
    const float* w31  = (const float*)d_in[10];
    const float* b31  = (const float*)d_in[11];
    const float* wf   = (const float*)d_in[12];
    const float* bf   = (const float*)d_in[13];
    const float* w1   = (const float*)d_in[14];
    const float* b1   = (const float*)d_in[15];
    const float* w2   = (const float*)d_in[16];
    const float* b2   = (const float*)d_in[17];
    const float* wl   = (const float*)d_in[18];
    const float* bl   = (const float*)d_in[19];
    const float* wr   = (const float*)d_in[20];
    const float* gamma= (const float*)d_in[21];
    const float* beta = (const float*)d_in[22];
    const float* wg   = (const float*)d_in[23];
    const float* bg   = (const float*)d_in[24];
    const float* we   = (const float*)d_in[25];
    const float* be   = (const float*)d_in[26];
    const float* wo   = (const float*)d_in[27];
    const float* bo   = (const float*)d_in[28];
    float* out = (float*)d_out;

    float* ws = (float*)d_ws;
    float* A  = ws;                        // x -> out L2
    float* Bq = ws + (size_t)NBSH;         // hsT -> out L0
    float* C  = ws + (size_t)2*NBSH;       // hr  -> out L1
    float* D  = ws + (size_t)3*NBSH;       // adj
    float2* part2 = (float2*)(ws + (size_t)4*NBSH);  // 1024*128 float2
    float* G = ws + (size_t)4*NBSH + 262144;
    float* W3    = G;                      // 48*128
    float* W5    = W3 + 48*HH;             // 80*128
    float* W31T  = W5 + 80*HH;             // 16*128
    float* Beff1 = W31T + 16*HH;           // 3*128
    float* Beff2 = Beff1 + 3*HH;           // 5*128
    float* scale = Beff2 + 5*HH;           // 3*128
    float* shift = scale + 3*HH;           // 3*128
    float* OL    = shift + 3*HH;           // 3*32*128

    k_prep<<<129, 128, 0, stream>>>(w11, b11, w12, w21, b21, w22, w31,
                                    W3, W5, W31T, Beff1, Beff2);
    k_front_fuse<<<512, 256, 0, stream>>>(data, W3, W5, W31T, Beff1, Beff2,
                                          b12, b22, b31, wf, bf, w1, b1,
                                          A, Bq, C);
    k_adj<<<512, 256, 0, stream>>>(Bq, C, w2, b2, gu, D);

    const float* inl[3] = {A, Bq, C};
    float* outl[3]      = {Bq, C, A};
    for (int l = 0; l < 3; ++l){
        int aff = (l > 0);
        const float* sc = scale + (l>0 ? (l-1)*HH : 0);
        const float* sh = shift + (l>0 ? (l-1)*HH : 0);
        k_gnn<<<512, 256, 0, stream>>>(D, inl[l], sc, sh, aff,
            wl + (size_t)l*HH*HH, bl + (size_t)l*HH, wr + (size_t)l*HH*HH,
            outl[l], part2);
        k_bnfin<<<HH, 256, 0, stream>>>(part2, gamma + (size_t)l*HH, beta + (size_t)l*HH,
            outl[l], scale + l*HH, shift + l*HH, OL + (size_t)l*BB*HH);
    }
    k_head<<<BB, 128, 0, stream>>>(OL, wg, bg, we, be, wo, bo, out);
}

// Round 5
// 171.225 us; speedup vs baseline: 1.2332x; 1.2332x over previous
//
#include <hip/hip_runtime.h>
#include <math.h>

#define BB 32
#define SS 128
#define DIN 16
#define HH 128
#define NBSH (BB*SS*HH)   // 524288

__device__ __forceinline__ float4 f4add(float4 a, float4 b){
    return make_float4(a.x+b.x, a.y+b.y, a.z+b.z, a.w+b.w);
}

// ============ K0a: coalesced-read transposes ==================================
// w12T[r*128+h] = w12[h*384+r]  (r = c*3+k), w22T[r*128+h] = w22[h*640+r],
// W31T[d*128+h] = w31[h*16+d]. float4 linear reads; scatter writes.
__global__ __launch_bounds__(256) void k_prep_t(
    const float* __restrict__ w12, const float* __restrict__ w22,
    const float* __restrict__ w31,
    float* __restrict__ w12T, float* __restrict__ w22T, float* __restrict__ W31T)
{
    int idx4 = blockIdx.x*256 + threadIdx.x;   // 130*256 = 33280 exactly
    if (idx4 < 12288){
        float4 v = reinterpret_cast<const float4*>(w12)[idx4];
        int e = idx4*4;
        const float* pv = (const float*)&v;
        #pragma unroll
        for (int u = 0; u < 4; ++u){
            int h = (e+u)/384, r = (e+u)%384;
            w12T[r*HH + h] = pv[u];
        }
    } else if (idx4 < 32768){
        int q = idx4 - 12288;
        float4 v = reinterpret_cast<const float4*>(w22)[q];
        int e = q*4;
        const float* pv = (const float*)&v;
        #pragma unroll
        for (int u = 0; u < 4; ++u){
            int h = (e+u)/640, r = (e+u)%640;
            w22T[r*HH + h] = pv[u];
        }
    } else if (idx4 < 33280){
        int q = idx4 - 32768;
        float4 v = reinterpret_cast<const float4*>(w31)[q];
        int e = q*4;
        const float* pv = (const float*)&v;
        #pragma unroll
        for (int u = 0; u < 4; ++u){
            int h = (e+u)/DIN, d = (e+u)%DIN;
            W31T[d*HH + h] = pv[u];
        }
    }
}

// ============ K0b: composite conv weights (coalesced in h) ====================
// W3[(k*16+d)*128+h] = sum_c w12T[(c*3+k)*128+h] * w11[c*16+d]; W5 similar.
// Beff1[k*128+h] = sum_c w12T[(c*3+k)*128+h] * b11[c]; Beff2 similar.
__global__ __launch_bounds__(128) void k_prep_w(
    const float* __restrict__ w12T, const float* __restrict__ w22T,
    const float* __restrict__ w11, const float* __restrict__ b11,
    const float* __restrict__ w21, const float* __restrict__ b21,
    float* __restrict__ W3, float* __restrict__ W5,
    float* __restrict__ Beff1, float* __restrict__ Beff2)
{
    int blk = blockIdx.x; int h = threadIdx.x;
    if (blk < 48){
        int k = blk >> 4, d = blk & 15;
        float acc = 0.f;
        #pragma unroll 4
        for (int c = 0; c < HH; ++c)
            acc = fmaf(w12T[(c*3+k)*HH + h], w11[c*DIN + d], acc);
        W3[(k*DIN+d)*HH + h] = acc;
    } else if (blk < 128){
        int kk = blk - 48; int k = kk >> 4, d = kk & 15;
        float acc = 0.f;
        #pragma unroll 4
        for (int c = 0; c < HH; ++c)
            acc = fmaf(w22T[(c*5+k)*HH + h], w21[c*DIN + d], acc);
        W5[(k*DIN+d)*HH + h] = acc;
    } else {
        int j = blk - 128;   // 0..7
        if (j < 3){
            float a = 0.f;
            #pragma unroll 4
            for (int c = 0; c < HH; ++c) a = fmaf(w12T[(c*3+j)*HH + h], b11[c], a);
            Beff1[j*HH + h] = a;
        } else {
            int k = j - 3;
            float a = 0.f;
            #pragma unroll 4
            for (int c = 0; c < HH; ++c) a = fmaf(w22T[(c*5+k)*HH + h], b21[c], a);
            Beff2[k*HH + h] = a;
        }
    }
}

// ============ K1: fused front end =============================================
__global__ __launch_bounds__(256) void k_front_fuse(
    const float* __restrict__ data,
    const float* __restrict__ W3, const float* __restrict__ W5,
    const float* __restrict__ W31T,
    const float* __restrict__ Beff1, const float* __restrict__ Beff2,
    const float* __restrict__ b12, const float* __restrict__ b22,
    const float* __restrict__ b31,
    const float* __restrict__ wf, const float* __restrict__ bf,
    const float* __restrict__ w1, const float* __restrict__ b1,
    float* __restrict__ x, float* __restrict__ hsT, float* __restrict__ hr)
{
    int blk = blockIdx.x; int b = blk >> 4; int s0 = (blk & 15) * 8;
    int t = threadIdx.x; int h = t & 127; int g = t >> 7; int tg = 4*g;
    __shared__ __align__(16) float dinT[DIN*28];   // [d][r], sp = s0-10+r
    __shared__ float4 xc1[2][HH], xc2[2][HH], xc3[2][HH];
    __shared__ float4 xL[2][HH];

    for (int idx = t; idx < 28*DIN; idx += 256){
        int r = idx >> 4, d = idx & 15;
        int sp = s0 - 10 + r;
        dinT[d*28 + r] = (sp >= 0 && sp < SS) ? data[(b*SS+sp)*DIN + d] : 0.f;
    }
    __syncthreads();

    float acc1[4] = {0,0,0,0}, acc2[4] = {0,0,0,0}, acc3[4] = {0,0,0,0};
    for (int d = 0; d < DIN; ++d){
        const float4* qp = reinterpret_cast<const float4*>(dinT + d*28 + tg);
        float4 q0=qp[0], q1=qp[1], q2=qp[2], q3=qp[3], q4=qp[4], q5=qp[5];
        float qf[24] = {q0.x,q0.y,q0.z,q0.w, q1.x,q1.y,q1.z,q1.w,
                        q2.x,q2.y,q2.z,q2.w, q3.x,q3.y,q3.z,q3.w,
                        q4.x,q4.y,q4.z,q4.w, q5.x,q5.y,q5.z,q5.w};
        #pragma unroll
        for (int k = 0; k < 3; ++k){
            float w = W3[(k*DIN+d)*HH + h];
            #pragma unroll
            for (int tp = 0; tp < 4; ++tp)
                acc1[tp] = fmaf(qf[tp + 3*k + 7], w, acc1[tp]);
        }
        #pragma unroll
        for (int k = 0; k < 5; ++k){
            float w = W5[(k*DIN+d)*HH + h];
            #pragma unroll
            for (int tp = 0; tp < 4; ++tp)
                acc2[tp] = fmaf(qf[tp + 5*k], w, acc2[tp]);
        }
        float w31v = W31T[d*HH + h];
        #pragma unroll
        for (int tp = 0; tp < 4; ++tp)
            acc3[tp] = fmaf(qf[tp + 10], w31v, acc3[tp]);
    }
    float be1[3] = {Beff1[h], Beff1[HH+h], Beff1[2*HH+h]};
    float be2[5] = {Beff2[h], Beff2[HH+h], Beff2[2*HH+h], Beff2[3*HH+h], Beff2[4*HH+h]};
    float bv12 = b12[h], bv22 = b22[h], bv31 = b31[h];
    float o1[4], o2[4], o3[4];
    #pragma unroll
    for (int tp = 0; tp < 4; ++tp){
        int s = s0 + tg + tp;
        float a1 = acc1[tp] + bv12;
        #pragma unroll
        for (int k = 0; k < 3; ++k)
            if ((unsigned)(s + 3*k - 3) < SS) a1 += be1[k];
        float a2 = acc2[tp] + bv22;
        #pragma unroll
        for (int k = 0; k < 5; ++k)
            if ((unsigned)(s + 5*k - 10) < SS) a2 += be2[k];
        o1[tp] = a1; o2[tp] = a2; o3[tp] = acc3[tp] + bv31;
    }
    xc1[g][h] = make_float4(o1[0],o1[1],o1[2],o1[3]);
    xc2[g][h] = make_float4(o2[0],o2[1],o2[2],o2[3]);
    xc3[g][h] = make_float4(o3[0],o3[1],o3[2],o3[3]);
    __syncthreads();

    float bfv = bf[h];
    float fa[4] = {bfv,bfv,bfv,bfv};
    for (int c = 0; c < HH; ++c){
        float4 a = xc1[g][c]; float w = wf[c*HH + h];
        fa[0]=fmaf(a.x,w,fa[0]); fa[1]=fmaf(a.y,w,fa[1]);
        fa[2]=fmaf(a.z,w,fa[2]); fa[3]=fmaf(a.w,w,fa[3]);
    }
    for (int c = 0; c < HH; ++c){
        float4 a = xc2[g][c]; float w = wf[(HH+c)*HH + h];
        fa[0]=fmaf(a.x,w,fa[0]); fa[1]=fmaf(a.y,w,fa[1]);
        fa[2]=fmaf(a.z,w,fa[2]); fa[3]=fmaf(a.w,w,fa[3]);
    }
    for (int c = 0; c < HH; ++c){
        float4 a = xc3[g][c]; float w = wf[(2*HH+c)*HH + h];
        fa[0]=fmaf(a.x,w,fa[0]); fa[1]=fmaf(a.y,w,fa[1]);
        fa[2]=fmaf(a.z,w,fa[2]); fa[3]=fmaf(a.w,w,fa[3]);
    }
    float4 xv = make_float4(fmaxf(fa[0],0.f), fmaxf(fa[1],0.f),
                            fmaxf(fa[2],0.f), fmaxf(fa[3],0.f));
    size_t base = (size_t)(b*SS + s0 + tg)*HH + h;
    x[base] = xv.x; x[base+HH] = xv.y; x[base+2*HH] = xv.z; x[base+3*HH] = xv.w;
    xL[g][h] = xv;
    __syncthreads();

    float as[4]={0,0,0,0}, ar[4]={0,0,0,0};
    for (int c = 0; c < HH; ++c){
        float4 a = xL[g][c];
        float wsv = w1[c*HH+h], wrv = w1[(HH+c)*HH+h];
        as[0]=fmaf(a.x,wsv,as[0]); as[1]=fmaf(a.y,wsv,as[1]);
        as[2]=fmaf(a.z,wsv,as[2]); as[3]=fmaf(a.w,wsv,as[3]);
        ar[0]=fmaf(a.x,wrv,ar[0]); ar[1]=fmaf(a.y,wrv,ar[1]);
        ar[2]=fmaf(a.z,wrv,ar[2]); ar[3]=fmaf(a.w,wrv,ar[3]);
    }
    float b1v = b1[h];
    *reinterpret_cast<float4*>(hsT + ((size_t)b*HH + h)*SS + s0 + tg) =
        make_float4(as[0], as[1], as[2], as[3]);
    hr[base]      = ar[0] + b1v;
    hr[base+HH]   = ar[1] + b1v;
    hr[base+2*HH] = ar[2] + b1v;
    hr[base+3*HH] = ar[3] + b1v;
}

// ============ K2: edge logits + gumbel argmax -> adj (8-i tile) ===============
__global__ __launch_bounds__(256) void k_adj(
    const float* __restrict__ hsT, const float* __restrict__ hr,
    const float* __restrict__ w2, const float* __restrict__ b2,
    const float* __restrict__ gu, float* __restrict__ adj)
{
    int blk = blockIdx.x; int b = blk >> 4; int i0 = (blk & 15) * 8;
    int t = threadIdx.x; int j = t & 127; int g = t >> 7; int ig = i0 + 4*g;
    __shared__ float4 hrT[2][HH];
    __shared__ float w20L[HH], w21L[HH];
    hrT[g][j] = make_float4(hr[(size_t)(b*SS+ig+0)*HH + j],
                            hr[(size_t)(b*SS+ig+1)*HH + j],
                            hr[(size_t)(b*SS+ig+2)*HH + j],
                            hr[(size_t)(b*SS+ig+3)*HH + j]);
    if (g == 0){ w20L[j] = w2[j*2]; w21L[j] = w2[j*2+1]; }
    __syncthreads();
    const float* hsb = hsT + (size_t)b*HH*SS;
    float d0[4] = {0,0,0,0}, d1[4] = {0,0,0,0};
    #pragma unroll 2
    for (int h = 0; h < HH; ++h){
        float hsv = hsb[h*SS + j];
        float4 hv = hrT[g][h];
        float wa = w20L[h], wb = w21L[h];
        float r0 = fmaxf(hsv + hv.x, 0.f);
        float r1 = fmaxf(hsv + hv.y, 0.f);
        float r2 = fmaxf(hsv + hv.z, 0.f);
        float r3 = fmaxf(hsv + hv.w, 0.f);
        d0[0]=fmaf(r0,wa,d0[0]); d1[0]=fmaf(r0,wb,d1[0]);
        d0[1]=fmaf(r1,wa,d0[1]); d1[1]=fmaf(r1,wb,d1[1]);
        d0[2]=fmaf(r2,wa,d0[2]); d1[2]=fmaf(r2,wb,d1[2]);
        d0[3]=fmaf(r3,wa,d0[3]); d1[3]=fmaf(r3,wb,d1[3]);
    }
    float b20 = b2[0], b21 = b2[1];
    #pragma unroll
    for (int ii = 0; ii < 4; ++ii){
        int i = ig + ii;
        size_t e = (size_t)(b*SS+i)*SS + j;
        float2 uv = *reinterpret_cast<const float2*>(gu + e*2);
        float u0 = fminf(fmaxf(uv.x, 1e-6f), 0.999999f);
        float u1 = fminf(fmaxf(uv.y, 1e-6f), 0.999999f);
        float g0 = -logf(-logf(u0));
        float g1 = -logf(-logf(u1));
        float y0 = d0[ii] + b20 + g0;
        float y1 = d1[ii] + b21 + g1;
        adj[e] = (j > i && y0 >= y1) ? 1.f : 0.f;
    }
}

// ============ K3: fused deg + agg + lin + BN partials (8-col tile) ============
__global__ __launch_bounds__(256) void k_gnn(
    const float* __restrict__ adj, const float* __restrict__ in,
    const float* __restrict__ scale_in, const float* __restrict__ shift_in, int aff,
    const float* __restrict__ wl, const float* __restrict__ bl,
    const float* __restrict__ wr,
    float* __restrict__ outb, float2* __restrict__ part2)
{
    int blk = blockIdx.x; int b = blk >> 4; int j0 = (blk & 15) * 8;
    int t = threadIdx.x; int h = t & 127; int g = t >> 7; int jg = j0 + 4*g;
    __shared__ __align__(16) float adjS[SS][8];
    __shared__ float4 red[2][64];
    __shared__ float4 aggL[2][HH], xnL[2][HH];

    // cooperative coalesced staging of adj[:, j0..j0+7]
    for (int idx = t; idx < SS*8; idx += 256){
        int i = idx >> 3, jj = idx & 7;
        adjS[i][jj] = adj[(size_t)(b*SS+i)*SS + j0 + jj];
    }
    float sc = aff ? scale_in[h] : 1.f;
    float sh = aff ? shift_in[h] : 0.f;
    __syncthreads();
    if (h < 64)
        red[g][h] = f4add(*reinterpret_cast<float4*>(&adjS[h][4*g]),
                          *reinterpret_cast<float4*>(&adjS[h+64][4*g]));
    __syncthreads();
    for (int off = 32; off; off >>= 1){
        if (h < off) red[g][h] = f4add(red[g][h], red[g][h+off]);
        __syncthreads();
    }
    float4 ds = red[g][0];
    float4 dv = make_float4(1.f/fmaxf(ds.x,1.f), 1.f/fmaxf(ds.y,1.f),
                            1.f/fmaxf(ds.z,1.f), 1.f/fmaxf(ds.w,1.f));
    float a0=0.f, a1=0.f, a2=0.f, a3=0.f;
    const float* inb = in + (size_t)b*SS*HH + h;
    #pragma unroll 4
    for (int i = 0; i < SS; ++i){
        float xv = fmaf(inb[(size_t)i*HH], sc, sh);
        float4 av = *reinterpret_cast<float4*>(&adjS[i][4*g]);
        a0=fmaf(av.x,xv,a0); a1=fmaf(av.y,xv,a1);
        a2=fmaf(av.z,xv,a2); a3=fmaf(av.w,xv,a3);
    }
    aggL[g][h] = make_float4(a0*dv.x, a1*dv.y, a2*dv.z, a3*dv.w);
    size_t base = (size_t)(b*SS+jg)*HH + h;
    xnL[g][h] = make_float4(fmaf(in[base],sc,sh), fmaf(in[base+HH],sc,sh),
                            fmaf(in[base+2*HH],sc,sh), fmaf(in[base+3*HH],sc,sh));
    __syncthreads();
    float bv = bl[h];
    float acc[4] = {bv,bv,bv,bv};
    for (int c = 0; c < HH; ++c){
        float4 gg = aggL[g][c]; float4 xv = xnL[g][c];
        float wlv = wl[c*HH+h], wrv = wr[c*HH+h];
        acc[0]=fmaf(gg.x,wlv,acc[0]); acc[0]=fmaf(xv.x,wrv,acc[0]);
        acc[1]=fmaf(gg.y,wlv,acc[1]); acc[1]=fmaf(xv.y,wrv,acc[1]);
        acc[2]=fmaf(gg.z,wlv,acc[2]); acc[2]=fmaf(xv.z,wrv,acc[2]);
        acc[3]=fmaf(gg.w,wlv,acc[3]); acc[3]=fmaf(xv.w,wrv,acc[3]);
    }
    outb[base]      = acc[0];
    outb[base+HH]   = acc[1];
    outb[base+2*HH] = acc[2];
    outb[base+3*HH] = acc[3];
    float psum = acc[0]+acc[1]+acc[2]+acc[3];
    float psq  = acc[0]*acc[0]+acc[1]*acc[1]+acc[2]*acc[2]+acc[3]*acc[3];
    part2[(size_t)(blk*2+g)*HH + h] = make_float2(psum, psq);
}

// ============ K4: BN finalize + capture normalized last row ===================
__global__ __launch_bounds__(256) void k_bnfin(
    const float2* __restrict__ part2, const float* __restrict__ gamma,
    const float* __restrict__ beta, const float* __restrict__ outb,
    float* __restrict__ scale, float* __restrict__ shift, float* __restrict__ ol)
{
    int h = blockIdx.x; int t = threadIdx.x;
    float s1 = 0.f, s2 = 0.f;
    for (int i = t; i < 1024; i += 256){
        float2 v = part2[(size_t)i*HH + h];
        s1 += v.x; s2 += v.y;
    }
    __shared__ float r1[256], r2[256];
    __shared__ float sc_sh[2];
    r1[t] = s1; r2[t] = s2;
    __syncthreads();
    for (int off = 128; off; off >>= 1){
        if (t < off){ r1[t] += r1[t+off]; r2[t] += r2[t+off]; }
        __syncthreads();
    }
    if (t == 0){
        float m = r1[0] * (1.f/4096.f);
        float v = r2[0] * (1.f/4096.f) - m*m;
        v = fmaxf(v, 0.f);
        float sc = gamma[h] / sqrtf(v + 1e-5f);
        float sh = beta[h] - m*sc;
        scale[h] = sc; shift[h] = sh;
        sc_sh[0] = sc; sc_sh[1] = sh;
    }
    __syncthreads();
    if (t < BB){
        float val = outb[((size_t)t*SS + SS-1)*HH + h];
        ol[t*HH + h] = fmaf(val, sc_sh[0], sc_sh[1]);
    }
}

// ============ K5: head (gate -> we -> wo) =====================================
__global__ __launch_bounds__(128) void k_head(
    const float* __restrict__ ol, const float* __restrict__ wg,
    const float* __restrict__ bg, const float* __restrict__ we,
    const float* __restrict__ be, const float* __restrict__ wo,
    const float* __restrict__ bo, float* __restrict__ out)
{
    int b = blockIdx.x; int t = threadIdx.x;
    __shared__ float xw[HH];
    float a = bg[0];
    #pragma unroll
    for (int l = 0; l < 3; ++l) a = fmaf(ol[(l*BB + b)*HH + t], wg[l], a);
    xw[t] = fmaxf(a, 0.f);
    __syncthreads();
    if (t < 64){
        float acc = be[t];
        for (int h = 0; h < HH; ++h) acc = fmaf(xw[h], we[h*64 + t], acc);
        float h2 = fmaxf(acc, 0.f);
        float r = h2 * wo[t];
        #pragma unroll
        for (int off = 32; off; off >>= 1) r += __shfl_down(r, off, 64);
        if (t == 0) out[b] = r + bo[0];
    }
}

// ==============================================================================
extern "C" void kernel_launch(void* const* d_in, const int* in_sizes, int n_in,
                              void* d_out, int out_size, void* d_ws, size_t ws_size,
                              hipStream_t stream)
{
    const float* data = (const float*)d_in[0];
    const float* gu   = (const float*)d_in[1];
    const float* w11  = (const float*)d_in[2];
    const float* b11  = (const float*)d_in[3];
    const float* w12  = (const float*)d_in[4];
    const float* b12  = (const float*)d_in[5];
    const float* w21  = (const float*)d_in[6];
    const float* b21  = (const float*)d_in[7];
    const float* w22  = (const float*)d_in[8];
    const float* b22  = (const float*)d_in[9];
    const float* w31  = (const float*)d_in[10];
    const float* b31  = (const float*)d_in[11];
    const float* wf   = (const float*)d_in[12];
    const float* bf   = (const float*)d_in[13];
    const float* w1   = (const float*)d_in[14];
    const float* b1   = (const float*)d_in[15];
    const float* w2   = (const float*)d_in[16];
    const float* b2   = (const float*)d_in[17];
    const float* wl   = (const float*)d_in[18];
    const float* bl   = (const float*)d_in[19];
    const float* wr   = (const float*)d_in[20];
    const float* gamma= (const float*)d_in[21];
    const float* beta = (const float*)d_in[22];
    const float* wg   = (const float*)d_in[23];
    const float* bg   = (const float*)d_in[24];
    const float* we   = (const float*)d_in[25];
    const float* be   = (const float*)d_in[26];
    const float* wo   = (const float*)d_in[27];
    const float* bo   = (const float*)d_in[28];
    float* out = (float*)d_out;

    float* ws = (float*)d_ws;
    float* A  = ws;                        // x -> out L2
    float* Bq = ws + (size_t)NBSH;         // hsT -> out L0
    float* C  = ws + (size_t)2*NBSH;       // hr  -> out L1
    float* D  = ws + (size_t)3*NBSH;       // adj
    float2* part2 = (float2*)(ws + (size_t)4*NBSH);  // 1024*128 float2
    float* G = ws + (size_t)4*NBSH + 262144;
    float* W3    = G;                      // 48*128
    float* W5    = W3 + 48*HH;             // 80*128
    float* W31T  = W5 + 80*HH;             // 16*128
    float* Beff1 = W31T + 16*HH;           // 3*128
    float* Beff2 = Beff1 + 3*HH;           // 5*128
    float* scale = Beff2 + 5*HH;           // 3*128
    float* shift = scale + 3*HH;           // 3*128
    float* OL    = shift + 3*HH;           // 3*32*128
    float* w12T  = OL + 3*BB*HH;           // 384*128
    float* w22T  = w12T + 384*HH;          // 640*128

    k_prep_t<<<130, 256, 0, stream>>>(w12, w22, w31, w12T, w22T, W31T);
    k_prep_w<<<136, 128, 0, stream>>>(w12T, w22T, w11, b11, w21, b21,
                                      W3, W5, Beff1, Beff2);
    k_front_fuse<<<512, 256, 0, stream>>>(data, W3, W5, W31T, Beff1, Beff2,
                                          b12, b22, b31, wf, bf, w1, b1,
                                          A, Bq, C);
    k_adj<<<512, 256, 0, stream>>>(Bq, C, w2, b2, gu, D);

    const float* inl[3] = {A, Bq, C};
    float* outl[3]      = {Bq, C, A};
    for (int l = 0; l < 3; ++l){
        int aff = (l > 0);
        const float* sc = scale + (l>0 ? (l-1)*HH : 0);
        const float* sh = shift + (l>0 ? (l-1)*HH : 0);
        k_gnn<<<512, 256, 0, stream>>>(D, inl[l], sc, sh, aff,
            wl + (size_t)l*HH*HH, bl + (size_t)l*HH, wr + (size_t)l*HH*HH,
            outl[l], part2);
        k_bnfin<<<HH, 256, 0, stream>>>(part2, gamma + (size_t)l*HH, beta + (size_t)l*HH,
            outl[l], scale + l*HH, shift + l*HH, OL + (size_t)l*BB*HH);
    }
    k_head<<<BB, 128, 0, stream>>>(OL, wg, bg, we, be, wo, bo, out);
}